// Round 1
// baseline (154.457 us; speedup 1.0000x reference)
//
#include <hip/hip_runtime.h>

typedef __attribute__((ext_vector_type(4))) float          f32x4;
typedef __attribute__((ext_vector_type(4))) unsigned int   u32x4;
typedef __attribute__((ext_vector_type(4))) unsigned short u16x4;

#define PI_F 3.14159265358979f

// round-to-nearest-even fp32 -> bf16
__device__ __forceinline__ unsigned short f2bf(float f) {
    unsigned int x = __float_as_uint(f);
    unsigned int r = ((x >> 16) & 1u) + 0x7fffu;
    return (unsigned short)((x + r) >> 16);
}

__device__ __forceinline__ void mfma16(f32x4& c, u32x4 a, u32x4 b) {
    asm volatile("v_mfma_f32_16x16x32_bf16 %0, %1, %2, %0"
                 : "+v"(c) : "v"(a), "v"(b));
}

// ---------------- prep kernels ----------------

// H[u][i][j] = h_u((i-j) mod 256), bf16.  8*65536 entries, 2048 blocks x 256.
__global__ void hbuild(unsigned short* __restrict__ H) {
    const int US[8] = {5, 22, 39, 57, 74, 92, 109, 127};
    int idx = blockIdx.x * 256 + threadIdx.x;
    int u = idx >> 16;
    int i = (idx >> 8) & 255, j = idx & 255;
    int d = (i - j) & 255;
    int m = 2 * US[u] + 1;
    float h;
    if (d == 0) {
        h = (float)m * (1.0f / 256.0f);
    } else {
        int t = (m * d) & 511;  // sin(pi*m*d/256) has period 512 in (m*d)
        float num = sinf((float)t * (PI_F / 256.0f));
        float den = sinf((float)d * (PI_F / 256.0f));
        h = num / (256.0f * den);
    }
    H[idx] = f2bf(h);
}

// x fp32 -> Xb bf16 (vectorized by 4); optionally write channel 0 of out.
__global__ void xconv(const float* __restrict__ x, unsigned short* __restrict__ Xb,
                      float* __restrict__ out, int write_c0) {
    int idx = blockIdx.x * 256 + threadIdx.x;  // 1,048,576 total
    f32x4 v = ((const f32x4*)x)[idx];
    u16x4 o = { f2bf(v.x), f2bf(v.y), f2bf(v.z), f2bf(v.w) };
    ((u16x4*)Xb)[idx] = o;
    if (write_c0) {
        size_t g = (size_t)idx * 4;
        out[(g + 0) * 9] = v.x;
        out[(g + 1) * 9] = v.y;
        out[(g + 2) * 9] = v.z;
        out[(g + 3) * 9] = v.w;
    }
}

// ---------------- GEMM core ----------------
// C(128x128) = A(128x256 row-major) * B(256x128), B given as Bt rows (Bt[j][k]).
// LDS tiles [128 rows][128 bytes] with XOR swizzle on byte bits 4-6.
#define SWZ(r, cb) (((unsigned)(r) * 128u) + ((unsigned)(cb) ^ ((((unsigned)(r)) & 7u) << 4)))

__device__ __forceinline__ void gemm_core(const char* __restrict__ Ab,
                                          const char* __restrict__ Bb,
                                          char* sA, char* sB, f32x4 acc[4][4]) {
    const int tid  = threadIdx.x;
    const int lane = tid & 63;
    const int wm   = (tid >> 7) & 1;   // wave row (2x2 waves)
    const int wn   = (tid >> 6) & 1;   // wave col
    const int lrow = lane & 15;
    const int lk   = lane >> 4;

    for (int kt = 0; kt < 4; ++kt) {   // K=256, BK=64
        if (kt) __syncthreads();
        u32x4 va[4], vb[4];
#pragma unroll
        for (int q = 0; q < 4; ++q) {
            int id = q * 256 + tid;
            int r = id >> 3, ch = id & 7;      // row 0..127, 16B-chunk 0..7
            va[q] = *(const u32x4*)(Ab + r * 512 + kt * 128 + ch * 16);
            vb[q] = *(const u32x4*)(Bb + r * 512 + kt * 128 + ch * 16);
        }
#pragma unroll
        for (int q = 0; q < 4; ++q) {
            int id = q * 256 + tid;
            int r = id >> 3, ch = id & 7;
            *(u32x4*)(sA + SWZ(r, ch * 16)) = va[q];
            *(u32x4*)(sB + SWZ(r, ch * 16)) = vb[q];
        }
        __syncthreads();
#pragma unroll
        for (int kk = 0; kk < 2; ++kk) {
            const int kb = kk * 64 + lk * 16;  // byte offset of this lane's 8 k's
            u32x4 af[4], bf[4];
#pragma unroll
            for (int mi = 0; mi < 4; ++mi) {
                int r = wm * 64 + mi * 16 + lrow;
                af[mi] = *(const u32x4*)(sA + SWZ(r, kb));
            }
#pragma unroll
            for (int ni = 0; ni < 4; ++ni) {
                int c = wn * 64 + ni * 16 + lrow;
                bf[ni] = *(const u32x4*)(sB + SWZ(c, kb));
            }
#pragma unroll
            for (int mi = 0; mi < 4; ++mi)
#pragma unroll
                for (int ni = 0; ni < 4; ++ni)
                    mfma16(acc[mi][ni], af[mi], bf[ni]);
        }
    }
    asm volatile("s_nop 7\n\ts_nop 7");  // drain MFMA before epilogue VALU reads
}

// stage1: T_u = X[n] * H_u ; store transposed bf16 Tt[j][i].
__global__ void __launch_bounds__(256) stage1(const unsigned short* __restrict__ Xb,
                                              const unsigned short* __restrict__ H,
                                              unsigned short* __restrict__ Tt, int u_off) {
    __shared__ char smem[32768];
    const int ti = blockIdx.x >> 1, tj = blockIdx.x & 1;
    const int n = blockIdx.y, ublk = blockIdx.z, u = u_off + ublk;
    const int i0 = ti * 128, j0 = tj * 128;

    const char* Ab = (const char*)(Xb + (size_t)n * 65536) + i0 * 512;
    const char* Bb = (const char*)(H + (size_t)u * 65536) + j0 * 512;  // H symmetric

    f32x4 acc[4][4];
#pragma unroll
    for (int a = 0; a < 4; ++a)
#pragma unroll
        for (int b = 0; b < 4; ++b) acc[a][b] = (f32x4){0.f, 0.f, 0.f, 0.f};

    gemm_core(Ab, Bb, smem, smem + 16384, acc);

    const int lane = threadIdx.x & 63;
    const int wm = (threadIdx.x >> 7) & 1, wn = (threadIdx.x >> 6) & 1;
    unsigned short* T = Tt + ((size_t)ublk * 64 + n) * 65536;
#pragma unroll
    for (int mi = 0; mi < 4; ++mi) {
        int ig = i0 + wm * 64 + mi * 16 + (lane >> 4) * 4;
#pragma unroll
        for (int ni = 0; ni < 4; ++ni) {
            int jg = j0 + wn * 64 + ni * 16 + (lane & 15);
            u16x4 o = { f2bf(acc[mi][ni].x), f2bf(acc[mi][ni].y),
                        f2bf(acc[mi][ni].z), f2bf(acc[mi][ni].w) };
            *(u16x4*)(T + (size_t)jg * 256 + ig) = o;  // Tt[j][i..i+3]
        }
    }
}

// stage2: Z_u = H_u * T_u.  direct=0: write fp32 Z to ws; direct=1: scatter to out.
__global__ void __launch_bounds__(256) stage2(const unsigned short* __restrict__ Tt,
                                              const unsigned short* __restrict__ H,
                                              float* __restrict__ Zf, float* __restrict__ out,
                                              int u_off, int direct) {
    __shared__ char smem[32768];
    const int ti = blockIdx.x >> 1, tj = blockIdx.x & 1;
    const int n = blockIdx.y, ublk = blockIdx.z, u = u_off + ublk;
    const int i0 = ti * 128, j0 = tj * 128;

    const char* Ab = (const char*)(H + (size_t)u * 65536) + i0 * 512;
    const char* Bb = (const char*)(Tt + ((size_t)ublk * 64 + n) * 65536) + j0 * 512;

    f32x4 acc[4][4];
#pragma unroll
    for (int a = 0; a < 4; ++a)
#pragma unroll
        for (int b = 0; b < 4; ++b) acc[a][b] = (f32x4){0.f, 0.f, 0.f, 0.f};

    gemm_core(Ab, Bb, smem, smem + 16384, acc);

    const int lane = threadIdx.x & 63;
    const int wm = (threadIdx.x >> 7) & 1, wn = (threadIdx.x >> 6) & 1;
    if (direct) {
#pragma unroll
        for (int mi = 0; mi < 4; ++mi) {
            int ig = i0 + wm * 64 + mi * 16 + (lane >> 4) * 4;
#pragma unroll
            for (int ni = 0; ni < 4; ++ni) {
                int jg = j0 + wn * 64 + ni * 16 + (lane & 15);
                float* o = out + ((((size_t)n * 256 + ig) * 256 + jg) * 9 + 1 + u);
                o[0]    = acc[mi][ni].x;
                o[2304] = acc[mi][ni].y;   // +1 image row = 256*9 floats
                o[4608] = acc[mi][ni].z;
                o[6912] = acc[mi][ni].w;
            }
        }
    } else {
        float* Z = Zf + ((size_t)ublk * 64 + n) * 65536;
#pragma unroll
        for (int mi = 0; mi < 4; ++mi) {
            int ig = i0 + wm * 64 + mi * 16 + (lane >> 4) * 4;
#pragma unroll
            for (int ni = 0; ni < 4; ++ni) {
                int jg = j0 + wn * 64 + ni * 16 + (lane & 15);
                float* o = Z + (size_t)ig * 256 + jg;
                o[0]   = acc[mi][ni].x;
                o[256] = acc[mi][ni].y;
                o[512] = acc[mi][ni].z;
                o[768] = acc[mi][ni].w;
            }
        }
    }
}

// Fully-coalesced channel interleave: out[g*9+0]=x[g], out[g*9+1+t]=Z[t][g].
__global__ void interleave(const float* __restrict__ x, const float* __restrict__ Zf,
                           float* __restrict__ out) {
    size_t g = (size_t)blockIdx.x * 256 + threadIdx.x;  // < 64*256*256
    float* o = out + g * 9;
    o[0] = x[g];
#pragma unroll
    for (int t = 0; t < 8; ++t) o[1 + t] = Zf[(size_t)t * 4194304 + g];
}

extern "C" void kernel_launch(void* const* d_in, const int* in_sizes, int n_in,
                              void* d_out, int out_size, void* d_ws, size_t ws_size,
                              hipStream_t stream) {
    const float* x = (const float*)d_in[0];
    float* out = (float*)d_out;
    char* ws = (char*)d_ws;

    unsigned short* H  = (unsigned short*)(ws);                // 1,048,576 B
    unsigned short* Xb = (unsigned short*)(ws + 1048576);      // 8,388,608 B
    unsigned short* Tt = (unsigned short*)(ws + 9437184);      // 67,108,864 B (all u)
    float*          Zf = (float*)(ws + 76546048);              // 134,217,728 B

    const size_t NEED_A = 210763776ull;  // H + Xb + Tt(all u) + Zf
    const size_t NEED_B = 76546048ull;   // H + Xb + Tt(all u)

    hbuild<<<2048, 256, 0, stream>>>(H);

    if (ws_size >= NEED_A) {
        xconv<<<4096, 256, 0, stream>>>(x, Xb, out, 0);
        stage1<<<dim3(4, 64, 8), 256, 0, stream>>>(Xb, H, Tt, 0);
        stage2<<<dim3(4, 64, 8), 256, 0, stream>>>(Tt, H, Zf, out, 0, 0);
        interleave<<<16384, 256, 0, stream>>>(x, Zf, out);
    } else if (ws_size >= NEED_B) {
        xconv<<<4096, 256, 0, stream>>>(x, Xb, out, 1);
        stage1<<<dim3(4, 64, 8), 256, 0, stream>>>(Xb, H, Tt, 0);
        stage2<<<dim3(4, 64, 8), 256, 0, stream>>>(Tt, H, nullptr, out, 0, 1);
    } else {
        // minimal-ws fallback: per-u sequencing, Tt holds one u-slice
        xconv<<<4096, 256, 0, stream>>>(x, Xb, out, 1);
        for (int u = 0; u < 8; ++u) {
            stage1<<<dim3(4, 64, 1), 256, 0, stream>>>(Xb, H, Tt, u);
            stage2<<<dim3(4, 64, 1), 256, 0, stream>>>(Tt, H, nullptr, out, u, 1);
        }
    }
}